// Round 16
// baseline (102.266 us; speedup 1.0000x reference)
//
#include <hip/hip_runtime.h>
#include <hip/hip_bf16.h>

// out = spline(x) @ proj_w^T + x @ res_w^T + proj_b
// A_bf16 = [spline(x) | x] : (16384, 2048),  Bcat_bf16 = [proj_w | res_w] : (1024, 2048)

#define IN_F   1024
#define OUT_F  1024
#define KNOTS  12
#define M_ROWS 16384
#define GK     2048

// ---- GEMM: 256x256 tile, BK=64, 16 waves (4Mx4N, wave=64x64), 16x16x32 MFMA
#define BM   256
#define BN   256
#define BKT  64
#define NTK  (GK / BKT)     // 32 K-tiles

typedef __attribute__((ext_vector_type(8))) __bf16 bf16x8;
typedef __attribute__((ext_vector_type(8))) unsigned short u16x8;
typedef __attribute__((ext_vector_type(4))) float  f32x4;

__device__ __forceinline__ unsigned short f2bf(float v) {
    unsigned int u = __float_as_uint(v);
    u = (u + 0x7fffu + ((u >> 16) & 1u)) >> 16;   // RNE
    return (unsigned short)u;
}
__device__ __forceinline__ float bf2f(unsigned short b) {
    return __uint_as_float(((unsigned int)b) << 16);
}

__device__ __forceinline__ void gload16(const void* g, void* l) {
    __builtin_amdgcn_global_load_lds(
        (const __attribute__((address_space(1))) void*)g,
        (__attribute__((address_space(3))) void*)l, 16, 0, 0);
}

// ---------------- prep (4 blocks) + B cast (2048 blocks), merged ------------
__global__ __launch_bounds__(256) void prep_bcast_kernel(
    const float* __restrict__ grid, const float* __restrict__ coeffs,
    const float* __restrict__ tangents, const float* __restrict__ alive,
    const float* __restrict__ P, const float* __restrict__ R,
    unsigned short* __restrict__ Bc,
    float* __restrict__ gmin, float* __restrict__ scale,
    float4* __restrict__ H, ushort4* __restrict__ Hb)
{
    const int blk = blockIdx.x;
    if (blk < 2048) {   // ---- bcast ----
        int g = blk*256 + threadIdx.x;
        int n  = g >> 9;
        int k4 = (g & 511) * 4;
        const float* src = (k4 < IN_F) ? (P + (size_t)n*IN_F + k4)
                                       : (R + (size_t)n*IN_F + (k4 - IN_F));
        float4 v = *reinterpret_cast<const float4*>(src);
        ushort4 o;
        o.x = f2bf(v.x); o.y = f2bf(v.y); o.z = f2bf(v.z); o.w = f2bf(v.w);
        *reinterpret_cast<ushort4*>(Bc + (size_t)n*GK + k4) = o;
        return;
    }
    // ---- prep ----
    int f = (blk - 2048) * 256 + threadIdx.x;
    if (f >= IN_F) return;
    float g[KNOTS], c[KNOTS], t[KNOTS], a[KNOTS];
    for (int i = 0; i < KNOTS; ++i) {
        g[i] = grid[f*KNOTS+i];  c[i] = coeffs[f*KNOTS+i];
        t[i] = tangents[f*KNOTS+i]; a[i] = alive[f*KNOTS+i];
    }
    for (int i = 1; i < KNOTS; ++i) {       // stable insertion sort on g
        float gk=g[i], ck=c[i], tk=t[i], ak=a[i];
        int j = i-1;
        while (j >= 0 && g[j] > gk) { g[j+1]=g[j]; c[j+1]=c[j]; t[j+1]=t[j]; a[j+1]=a[j]; --j; }
        g[j+1]=gk; c[j+1]=ck; t[j+1]=tk; a[j+1]=ak;
    }
    float mcl[KNOTS], mtl[KNOTS];
    for (int i = 0; i < KNOTS; ++i) {
        float s = 1.f / (1.f + expf(-a[i]));
        mcl[i] = c[i]*s;  mtl[i] = t[i]*s;
    }
    gmin[f] = g[0];
    float grange = fmaxf(g[KNOTS-1] - g[0], 1e-6f);
    scale[f] = (float)(KNOTS-1) / grange;
    for (int k = 0; k < KNOTS-1; ++k) {
        float dx = fmaxf(g[k+1]-g[k], 1e-6f);
        float4 h = make_float4(mcl[k], mcl[k+1], mtl[k]*dx, mtl[k+1]*dx);
        H[(size_t)f*KNOTS + k] = h;
        Hb[(size_t)f*KNOTS + k] = make_ushort4(f2bf(h.x), f2bf(h.y), f2bf(h.z), f2bf(h.w));
    }
    H[(size_t)f*KNOTS + KNOTS-1]  = make_float4(0.f, 0.f, 0.f, 0.f);
    Hb[(size_t)f*KNOTS + KNOTS-1] = make_ushort4(0, 0, 0, 0);
}

// ---------------- spline + cast:  A = [spline(x) | x]  bf16 -----------------
// v3: thread owns 8 consecutive features (lanes 0-31 of each half-wave span a
// contiguous 1KB x-segment); 8 row-iters of {2x16B loads, 8 evals, 2x16B
// stores} — half the memory instructions of v2, double per-iter ILP.
// bf16 tables: 26 KiB LDS -> 6 blocks/CU (24 waves/CU).
#define SROWS 64
#define HPAD  13
__global__ __launch_bounds__(256, 6) void spline_kernel(const float* __restrict__ x,
    const float* __restrict__ gmin, const float* __restrict__ scale,
    const ushort4* __restrict__ Hb, unsigned short* __restrict__ A)
{
    __shared__ ushort4 sH[256 * HPAD];    // 26 KiB
    const int tid  = threadIdx.x;
    const int fblk = blockIdx.y * 256;
    #pragma unroll
    for (int k = 0; k < KNOTS; ++k) sH[tid*HPAD + k] = Hb[(size_t)(fblk+tid)*KNOTS + k];
    __syncthreads();

    const int f0 = (tid & 31) * 8;        // feature offset within 256-slice
    const int rg = tid >> 5;              // row group 0..7
    float gms[8], scs[8];
    #pragma unroll
    for (int e = 0; e < 8; e += 4) {
        const float4 g4 = *reinterpret_cast<const float4*>(gmin + fblk + f0 + e);
        const float4 s4 = *reinterpret_cast<const float4*>(scale + fblk + f0 + e);
        gms[e]=g4.x; gms[e+1]=g4.y; gms[e+2]=g4.z; gms[e+3]=g4.w;
        scs[e]=s4.x; scs[e+1]=s4.y; scs[e+2]=s4.z; scs[e+3]=s4.w;
    }
    const int r0 = blockIdx.x * SROWS;

    #pragma unroll 4
    for (int r = rg; r < SROWS; r += 8) {
        const int row = r0 + r;
        const float* xp4 = x + (size_t)row*IN_F + fblk + f0;
        const float4 xv0 = *reinterpret_cast<const float4*>(xp4);
        const float4 xv1 = *reinterpret_cast<const float4*>(xp4 + 4);
        const float xs[8] = {xv0.x,xv0.y,xv0.z,xv0.w, xv1.x,xv1.y,xv1.z,xv1.w};
        u16x8 so, xo;
        #pragma unroll
        for (int j = 0; j < 8; ++j) {
            const float xi = xs[j];
            float xn = (xi - gms[j]) * scs[j];
            xn = fminf(fmaxf(xn, 0.f), (float)(KNOTS-1));
            int idx = (int)xn;  idx = idx > (KNOTS-2) ? (KNOTS-2) : idx;
            const float tt = xn - (float)idx;
            const ushort4 hb = sH[(f0+j)*HPAD + idx];
            const float hx = bf2f(hb.x), hy = bf2f(hb.y), hz = bf2f(hb.z), hw = bf2f(hb.w);
            const float t2 = tt*tt, t3 = t2*tt;
            const float h00 =  2.f*t3 - 3.f*t2 + 1.f;
            const float h01 = -2.f*t3 + 3.f*t2;
            const float h10 =  t3 - 2.f*t2 + tt;
            const float h11 =  t3 - t2;
            so[j] = f2bf(h00*hx + h01*hy + h10*hz + h11*hw);
            xo[j] = f2bf(xi);
        }
        const size_t base = (size_t)row * GK + fblk + f0;
        *reinterpret_cast<u16x8*>(A + base)        = so;
        *reinterpret_cast<u16x8*>(A + base + IN_F) = xo;
    }
}

// ---------------- GEMM: C = A @ Bcat^T + bias -------------------------------
// R9/R12 structure (proven best: 63.6-64us, MfmaUtil 45-47, 0 conflicts,
// 64 VGPR). 1024 threads = 16 waves (4/SIMD latency rotation), wave tile
// 64x64, BK=64, 2-deep buffer, ONE exact vmcnt(0) + ONE barrier per K-tile,
// merged {frag reads | stage(t+1) | MFMA} region (compiler interleaves
// lgkmcnt with MFMAs). Cross-wave staging safe ONLY with vmcnt+barrier per
// tile (R11: vmcnt is per-wave; barrier is the only cross-wave primitive).
// Tested-and-rejected variants: 4-phase sched (R5/R6 neutral), 32x32 MFMA
// (R7 -15%), fused spline staging (R8 -3x), BK=32 3-deep (R10 neutral),
// barrier-per-2-tiles (R11 race), 2 blocks/CU BK=32 (R14 -21%).
// XOR swizzle (16B slot ^= row&7) on global source AND ds_read (involution).
__global__ __launch_bounds__(1024, 4) void gemm_kernel(
    const unsigned short* __restrict__ A, const unsigned short* __restrict__ B,
    const float* __restrict__ bias, float* __restrict__ C)
{
    __shared__ unsigned short sA[2][BM*BKT];   // 2 x 32 KiB
    __shared__ unsigned short sB[2][BN*BKT];   // 2 x 32 KiB => 128 KiB

    const int tid  = threadIdx.x;
    const int wg   = blockIdx.x;                  // 256 wgs, %8==0 bijective
    const int swzb = (wg & 7) * 32 + (wg >> 3);
    const int by   = swzb >> 2;                   // 0..63
    const int bx   = swzb & 3;                    // 0..3

    const int lane = tid & 63;
    const int wave = tid >> 6;       // 0..15
    const int wm   = wave >> 2;      // 0..3  (64-row group)
    const int wn   = wave & 3;       // 0..3  (64-col group)
    const int lr   = lane & 15;
    const int lsl  = lane >> 4;      // 0..3

    const size_t aRow0 = (size_t)by * BM;
    const size_t bRow0 = (size_t)bx * BN;

    // stage full 256x64 tile: 2048 16B units, 2 per thread
    auto stage = [&](const unsigned short* __restrict__ G, size_t gRow0,
                     unsigned short* lds, int ts) {
        const int k0 = ts * BKT;
        #pragma unroll
        for (int i = 0; i < 2; ++i) {
            const int L16  = i*1024 + tid;
            const int lrow = L16 >> 3;                // 0..255
            const int ss   = (L16 & 7) ^ (lrow & 7);  // pre-swizzled source slot
            gload16(G + (gRow0 + lrow)*GK + k0 + ss*8, lds + (size_t)L16*8);
        }
    };
    auto rd = [&](const unsigned short* s, int lrow, int ks) -> bf16x8 {
        const int sp = (ks*4 + lsl) ^ (lrow & 7);
        return *reinterpret_cast<const bf16x8*>(s + lrow*BKT + sp*8);
    };

    f32x4 acc[4][4] = {};

    // prologue: stage tile 0
    stage(A, aRow0, &sA[0][0], 0);
    stage(B, bRow0, &sB[0][0], 0);

    for (int t = 0; t < NTK; ++t) {
        const int b = t & 1;
        const unsigned short* cA = &sA[b][0];
        const unsigned short* cB = &sB[b][0];

        asm volatile("s_waitcnt vmcnt(0)" ::: "memory");
        __builtin_amdgcn_s_barrier();

        // ---- ks = 0: 8 frag reads; stage(t+1); 16 MFMA ----
        {
            bf16x8 av[4], bv[4];
            #pragma unroll
            for (int m = 0; m < 4; ++m) av[m] = rd(cA, wm*64 + m*16 + lr, 0);
            #pragma unroll
            for (int n = 0; n < 4; ++n) bv[n] = rd(cB, wn*64 + n*16 + lr, 0);
            if (t + 1 < NTK) {
                stage(A, aRow0, &sA[b^1][0], t+1);
                stage(B, bRow0, &sB[b^1][0], t+1);
            }
            __builtin_amdgcn_s_setprio(1);
            #pragma unroll
            for (int m = 0; m < 4; ++m)
              #pragma unroll
              for (int n = 0; n < 4; ++n)
                acc[m][n] = __builtin_amdgcn_mfma_f32_16x16x32_bf16(av[m], bv[n], acc[m][n], 0, 0, 0);
            __builtin_amdgcn_s_setprio(0);
        }
        // ---- ks = 1: 8 frag reads; 16 MFMA ----
        {
            bf16x8 av[4], bv[4];
            #pragma unroll
            for (int m = 0; m < 4; ++m) av[m] = rd(cA, wm*64 + m*16 + lr, 1);
            #pragma unroll
            for (int n = 0; n < 4; ++n) bv[n] = rd(cB, wn*64 + n*16 + lr, 1);
            __builtin_amdgcn_s_setprio(1);
            #pragma unroll
            for (int m = 0; m < 4; ++m)
              #pragma unroll
              for (int n = 0; n < 4; ++n)
                acc[m][n] = __builtin_amdgcn_mfma_f32_16x16x32_bf16(av[m], bv[n], acc[m][n], 0, 0, 0);
            __builtin_amdgcn_s_setprio(0);
        }
    }

    // epilogue: C = acc + bias   (C/D map: col = lane&15, row = (lane>>4)*4 + r)
    #pragma unroll
    for (int n = 0; n < 4; ++n) {
        const int col = bx*BN + wn*64 + n*16 + lr;
        const float bv = bias[col];
        #pragma unroll
        for (int m = 0; m < 4; ++m) {
            const int grow = by*BM + wm*64 + m*16 + lsl*4;
            #pragma unroll
            for (int r = 0; r < 4; ++r)
                C[(size_t)(grow + r)*OUT_F + col] = acc[m][n][r] + bv;
        }
    }
}

// ---------------- fallback (ws too small): fused fp32, slow but correct -----
__global__ __launch_bounds__(256) void fallback_prep_kernel(
    const float* __restrict__ grid, const float* __restrict__ coeffs,
    const float* __restrict__ tangents, const float* __restrict__ alive,
    float* __restrict__ gmin, float* __restrict__ scale, float4* __restrict__ H)
{
    int f = blockIdx.x * blockDim.x + threadIdx.x;
    if (f >= IN_F) return;
    float g[KNOTS], c[KNOTS], t[KNOTS], a[KNOTS];
    for (int i = 0; i < KNOTS; ++i) {
        g[i] = grid[f*KNOTS+i];  c[i] = coeffs[f*KNOTS+i];
        t[i] = tangents[f*KNOTS+i]; a[i] = alive[f*KNOTS+i];
    }
    for (int i = 1; i < KNOTS; ++i) {
        float gk=g[i], ck=c[i], tk=t[i], ak=a[i];
        int j = i-1;
        while (j >= 0 && g[j] > gk) { g[j+1]=g[j]; c[j+1]=c[j]; t[j+1]=t[j]; a[j+1]=a[j]; --j; }
        g[j+1]=gk; c[j+1]=ck; t[j+1]=tk; a[j+1]=ak;
    }
    float mcl[KNOTS], mtl[KNOTS];
    for (int i = 0; i < KNOTS; ++i) {
        float s = 1.f / (1.f + expf(-a[i]));
        mcl[i] = c[i]*s;  mtl[i] = t[i]*s;
    }
    gmin[f] = g[0];
    float grange = fmaxf(g[KNOTS-1] - g[0], 1e-6f);
    scale[f] = (float)(KNOTS-1) / grange;
    for (int k = 0; k < KNOTS-1; ++k) {
        float dx = fmaxf(g[k+1]-g[k], 1e-6f);
        H[(size_t)f*KNOTS + k] = make_float4(mcl[k], mcl[k+1], mtl[k]*dx, mtl[k+1]*dx);
    }
    H[(size_t)f*KNOTS + KNOTS-1] = make_float4(0.f, 0.f, 0.f, 0.f);
}

__global__ __launch_bounds__(256) void fallback_kernel(
    const float* __restrict__ x, const float* __restrict__ P,
    const float* __restrict__ R, const float* __restrict__ pb,
    const float* __restrict__ gmin, const float* __restrict__ scale,
    const float4* __restrict__ H, float* __restrict__ out)
{
    __shared__ float s_s[IN_F];
    __shared__ float s_x[IN_F];
    int row = blockIdx.x;
    const float* xr = x + (size_t)row*IN_F;
    for (int f = threadIdx.x; f < IN_F; f += 256) {
        float xi = xr[f];
        float xn = (xi - gmin[f]) * scale[f];
        xn = fminf(fmaxf(xn, 0.f), (float)(KNOTS-1));
        int idx = (int)xn;  idx = idx > (KNOTS-2) ? (KNOTS-2) : idx;
        float tt = xn - (float)idx;
        float4 h = H[(size_t)f*KNOTS + idx];
        float t2 = tt*tt, t3 = t2*tt;
        s_s[f] = (2.f*t3-3.f*t2+1.f)*h.x + (-2.f*t3+3.f*t2)*h.y
               + (t3-2.f*t2+tt)*h.z + (t3-t2)*h.w;
        s_x[f] = xi;
    }
    __syncthreads();
    for (int j = 0; j < 4; ++j) {
        int o = threadIdx.x + j*256;
        const float* Pr = P + (size_t)o*IN_F;
        const float* Rr = R + (size_t)o*IN_F;
        float acc = pb[o];
        for (int f = 0; f < IN_F; ++f)
            acc = fmaf(s_s[f], Pr[f], fmaf(s_x[f], Rr[f], acc));
        out[(size_t)row*OUT_F + o] = acc;
    }
}

extern "C" void kernel_launch(void* const* d_in, const int* in_sizes, int n_in,
                              void* d_out, int out_size, void* d_ws, size_t ws_size,
                              hipStream_t stream) {
    const float* x         = (const float*)d_in[0];
    const float* grid      = (const float*)d_in[1];
    const float* coeffs    = (const float*)d_in[2];
    const float* tangents  = (const float*)d_in[3];
    const float* knotalive = (const float*)d_in[4];
    const float* proj_w    = (const float*)d_in[5];
    const float* proj_b    = (const float*)d_in[6];
    const float* res_w     = (const float*)d_in[7];
    float* out = (float*)d_out;

    const size_t needB  = (size_t)OUT_F * GK * 2;                 // 4 MiB
    const size_t needA  = (size_t)M_ROWS * GK * 2;                // 64 MiB
    const size_t needT  = ((size_t)IN_F*2 + (size_t)IN_F*KNOTS*4) * 4
                        + (size_t)IN_F*KNOTS*8;                   // + Hb

    char* ws = (char*)d_ws;
    if (ws_size >= needB + needA + needT) {
        unsigned short* Bcat = (unsigned short*)ws;
        unsigned short* Abuf = (unsigned short*)(ws + needB);
        float*   gmin = (float*)(ws + needB + needA);
        float*   scl  = gmin + IN_F;
        float4*  H    = (float4*)(scl + IN_F);
        ushort4* Hb   = (ushort4*)(H + (size_t)IN_F*KNOTS);

        prep_bcast_kernel<<<2048 + IN_F/256, 256, 0, stream>>>(
            grid, coeffs, tangents, knotalive, proj_w, res_w, Bcat, gmin, scl, H, Hb);
        spline_kernel<<<dim3(M_ROWS/SROWS, IN_F/256), 256, 0, stream>>>(x, gmin, scl, Hb, Abuf);
        gemm_kernel<<<(M_ROWS/BM)*(OUT_F/BN), 1024, 0, stream>>>(Abuf, Bcat, proj_b, out);
    } else {
        float*  gmin = (float*)ws;
        float*  scl  = gmin + IN_F;
        float4* H    = (float4*)(scl + IN_F);
        fallback_prep_kernel<<<(IN_F+255)/256, 256, 0, stream>>>(grid, coeffs, tangents, knotalive,
                                                                 gmin, scl, H);
        fallback_kernel<<<M_ROWS, 256, 0, stream>>>(x, proj_w, res_w, proj_b,
                                                    gmin, scl, H, out);
    }
}

// Round 17
// 101.638 us; speedup vs baseline: 1.0062x; 1.0062x over previous
//
#include <hip/hip_runtime.h>
#include <hip/hip_bf16.h>

// out = spline(x) @ proj_w^T + x @ res_w^T + proj_b
// A_bf16 = [spline(x) | x] : (16384, 2048),  Bcat_bf16 = [proj_w | res_w] : (1024, 2048)

#define IN_F   1024
#define OUT_F  1024
#define KNOTS  12
#define M_ROWS 16384
#define GK     2048

// ---- GEMM: 256x256 tile, BK=64, 16 waves (4Mx4N, wave=64x64), 16x16x32 MFMA
#define BM   256
#define BN   256
#define BKT  64
#define NTK  (GK / BKT)     // 32 K-tiles

typedef __attribute__((ext_vector_type(8))) __bf16 bf16x8;
typedef __attribute__((ext_vector_type(8))) unsigned short u16x8;
typedef __attribute__((ext_vector_type(4))) float  f32x4;

__device__ __forceinline__ unsigned short f2bf(float v) {
    unsigned int u = __float_as_uint(v);
    u = (u + 0x7fffu + ((u >> 16) & 1u)) >> 16;   // RNE
    return (unsigned short)u;
}
__device__ __forceinline__ float bf2f(unsigned short b) {
    return __uint_as_float(((unsigned int)b) << 16);
}

__device__ __forceinline__ void gload16(const void* g, void* l) {
    __builtin_amdgcn_global_load_lds(
        (const __attribute__((address_space(1))) void*)g,
        (__attribute__((address_space(3))) void*)l, 16, 0, 0);
}

// ---------------- prep (4 blocks) + B cast (2048 blocks), merged ------------
__global__ __launch_bounds__(256) void prep_bcast_kernel(
    const float* __restrict__ grid, const float* __restrict__ coeffs,
    const float* __restrict__ tangents, const float* __restrict__ alive,
    const float* __restrict__ P, const float* __restrict__ R,
    unsigned short* __restrict__ Bc,
    float* __restrict__ gmin, float* __restrict__ scale,
    float4* __restrict__ H, ushort4* __restrict__ Hb)
{
    const int blk = blockIdx.x;
    if (blk < 2048) {   // ---- bcast ----
        int g = blk*256 + threadIdx.x;
        int n  = g >> 9;
        int k4 = (g & 511) * 4;
        const float* src = (k4 < IN_F) ? (P + (size_t)n*IN_F + k4)
                                       : (R + (size_t)n*IN_F + (k4 - IN_F));
        float4 v = *reinterpret_cast<const float4*>(src);
        ushort4 o;
        o.x = f2bf(v.x); o.y = f2bf(v.y); o.z = f2bf(v.z); o.w = f2bf(v.w);
        *reinterpret_cast<ushort4*>(Bc + (size_t)n*GK + k4) = o;
        return;
    }
    // ---- prep ----
    int f = (blk - 2048) * 256 + threadIdx.x;
    if (f >= IN_F) return;
    float g[KNOTS], c[KNOTS], t[KNOTS], a[KNOTS];
    for (int i = 0; i < KNOTS; ++i) {
        g[i] = grid[f*KNOTS+i];  c[i] = coeffs[f*KNOTS+i];
        t[i] = tangents[f*KNOTS+i]; a[i] = alive[f*KNOTS+i];
    }
    for (int i = 1; i < KNOTS; ++i) {       // stable insertion sort on g
        float gk=g[i], ck=c[i], tk=t[i], ak=a[i];
        int j = i-1;
        while (j >= 0 && g[j] > gk) { g[j+1]=g[j]; c[j+1]=c[j]; t[j+1]=t[j]; a[j+1]=a[j]; --j; }
        g[j+1]=gk; c[j+1]=ck; t[j+1]=tk; a[j+1]=ak;
    }
    float mcl[KNOTS], mtl[KNOTS];
    for (int i = 0; i < KNOTS; ++i) {
        float s = 1.f / (1.f + expf(-a[i]));
        mcl[i] = c[i]*s;  mtl[i] = t[i]*s;
    }
    gmin[f] = g[0];
    float grange = fmaxf(g[KNOTS-1] - g[0], 1e-6f);
    scale[f] = (float)(KNOTS-1) / grange;
    for (int k = 0; k < KNOTS-1; ++k) {
        float dx = fmaxf(g[k+1]-g[k], 1e-6f);
        float4 h = make_float4(mcl[k], mcl[k+1], mtl[k]*dx, mtl[k+1]*dx);
        H[(size_t)f*KNOTS + k] = h;
        Hb[(size_t)f*KNOTS + k] = make_ushort4(f2bf(h.x), f2bf(h.y), f2bf(h.z), f2bf(h.w));
    }
    H[(size_t)f*KNOTS + KNOTS-1]  = make_float4(0.f, 0.f, 0.f, 0.f);
    Hb[(size_t)f*KNOTS + KNOTS-1] = make_ushort4(0, 0, 0, 0);
}

// ---------------- spline + cast:  A = [spline(x) | x]  bf16 -----------------
// v4: 128-feature slices -> 13 KiB LDS -> 8 blocks/CU = 32 waves/CU (HW cap).
// Thread owns 8 consecutive features; 16 lanes span a contiguous 512B
// x-segment; 4 row-iters of {2x16B loads, 8 evals, 2x16B stores}.
#define SROWS 64
#define HPAD  13
__global__ __launch_bounds__(256, 8) void spline_kernel(const float* __restrict__ x,
    const float* __restrict__ gmin, const float* __restrict__ scale,
    const ushort4* __restrict__ Hb, unsigned short* __restrict__ A)
{
    __shared__ ushort4 sH[128 * HPAD];    // 13 KiB
    const int tid  = threadIdx.x;
    const int fblk = blockIdx.y * 128;
    if (tid < 128) {
        #pragma unroll
        for (int k = 0; k < KNOTS; ++k) sH[tid*HPAD + k] = Hb[(size_t)(fblk+tid)*KNOTS + k];
    }
    __syncthreads();

    const int fi = (tid & 15) * 8;        // feature offset within 128-slice
    const int rg = tid >> 4;              // row group 0..15
    float gms[8], scs[8];
    #pragma unroll
    for (int e = 0; e < 8; e += 4) {
        const float4 g4 = *reinterpret_cast<const float4*>(gmin + fblk + fi + e);
        const float4 s4 = *reinterpret_cast<const float4*>(scale + fblk + fi + e);
        gms[e]=g4.x; gms[e+1]=g4.y; gms[e+2]=g4.z; gms[e+3]=g4.w;
        scs[e]=s4.x; scs[e+1]=s4.y; scs[e+2]=s4.z; scs[e+3]=s4.w;
    }
    const int r0 = blockIdx.x * SROWS;

    #pragma unroll 4
    for (int r = rg; r < SROWS; r += 16) {
        const int row = r0 + r;
        const float* xp4 = x + (size_t)row*IN_F + fblk + fi;
        const float4 xv0 = *reinterpret_cast<const float4*>(xp4);
        const float4 xv1 = *reinterpret_cast<const float4*>(xp4 + 4);
        const float xs[8] = {xv0.x,xv0.y,xv0.z,xv0.w, xv1.x,xv1.y,xv1.z,xv1.w};
        u16x8 so, xo;
        #pragma unroll
        for (int j = 0; j < 8; ++j) {
            const float xi = xs[j];
            float xn = (xi - gms[j]) * scs[j];
            xn = fminf(fmaxf(xn, 0.f), (float)(KNOTS-1));
            int idx = (int)xn;  idx = idx > (KNOTS-2) ? (KNOTS-2) : idx;
            const float tt = xn - (float)idx;
            const ushort4 hb = sH[(fi+j)*HPAD + idx];
            const float hx = bf2f(hb.x), hy = bf2f(hb.y), hz = bf2f(hb.z), hw = bf2f(hb.w);
            const float t2 = tt*tt, t3 = t2*tt;
            const float h00 =  2.f*t3 - 3.f*t2 + 1.f;
            const float h01 = -2.f*t3 + 3.f*t2;
            const float h10 =  t3 - 2.f*t2 + tt;
            const float h11 =  t3 - t2;
            so[j] = f2bf(h00*hx + h01*hy + h10*hz + h11*hw);
            xo[j] = f2bf(xi);
        }
        const size_t base = (size_t)row * GK + fblk + fi;
        *reinterpret_cast<u16x8*>(A + base)        = so;
        *reinterpret_cast<u16x8*>(A + base + IN_F) = xo;
    }
}

// ---------------- GEMM: C = A @ Bcat^T + bias -------------------------------
// R9/R12 K-loop (proven best: 63.6-64us, MfmaUtil 45-47, 0 conflicts, 64
// VGPR): 16 waves, wave tile 64x64, BK=64, 2-deep buffer, ONE exact vmcnt(0)
// + ONE barrier per K-tile, merged {frag reads | stage(t+1) | MFMA}.
// NEW (this round): f32x4 epilogue — per-wave 8KB LDS transpose (2 chunks of
// 32x64 f32) so C is written as 16B stores covering full 256B row segments
// (was 64 scalar 4B stores; WRITE_SIZE 78MB vs 64 ideal). One __syncthreads
// after the K-loop makes staging-buffer reuse race-free.
// Tested-and-rejected K-loop variants: 4-phase (R5/R6 neutral), 32x32 MFMA
// (R7 -15%), fused staging (R8 -3x), BK=32 3-deep (R10 neutral), barrier-per-
// 2-tiles (R11 race), 2 blocks/CU BK=32 (R14 -21%).
__global__ __launch_bounds__(1024, 4) void gemm_kernel(
    const unsigned short* __restrict__ A, const unsigned short* __restrict__ B,
    const float* __restrict__ bias, float* __restrict__ C)
{
    __shared__ __align__(16) char smem[2*(BM*BKT + BN*BKT)*2];   // 128 KiB
    unsigned short* sAbase = (unsigned short*)smem;              // 2 x 32 KiB
    unsigned short* sBbase = sAbase + 2*BM*BKT;                  // 2 x 32 KiB

    const int tid  = threadIdx.x;
    const int wg   = blockIdx.x;                  // 256 wgs, %8==0 bijective
    const int swzb = (wg & 7) * 32 + (wg >> 3);
    const int by   = swzb >> 2;                   // 0..63
    const int bx   = swzb & 3;                    // 0..3

    const int lane = tid & 63;
    const int wave = tid >> 6;       // 0..15
    const int wm   = wave >> 2;      // 0..3  (64-row group)
    const int wn   = wave & 3;       // 0..3  (64-col group)
    const int lr   = lane & 15;
    const int lsl  = lane >> 4;      // 0..3

    const size_t aRow0 = (size_t)by * BM;
    const size_t bRow0 = (size_t)bx * BN;

    // stage full 256x64 tile: 2048 16B units, 2 per thread
    auto stage = [&](const unsigned short* __restrict__ G, size_t gRow0,
                     unsigned short* lds, int ts) {
        const int k0 = ts * BKT;
        #pragma unroll
        for (int i = 0; i < 2; ++i) {
            const int L16  = i*1024 + tid;
            const int lrow = L16 >> 3;                // 0..255
            const int ss   = (L16 & 7) ^ (lrow & 7);  // pre-swizzled source slot
            gload16(G + (gRow0 + lrow)*GK + k0 + ss*8, lds + (size_t)L16*8);
        }
    };
    auto rd = [&](const unsigned short* s, int lrow, int ks) -> bf16x8 {
        const int sp = (ks*4 + lsl) ^ (lrow & 7);
        return *reinterpret_cast<const bf16x8*>(s + lrow*BKT + sp*8);
    };

    f32x4 acc[4][4] = {};

    // prologue: stage tile 0
    stage(A, aRow0, sAbase, 0);
    stage(B, bRow0, sBbase, 0);

    for (int t = 0; t < NTK; ++t) {
        const int b = t & 1;
        const unsigned short* cA = sAbase + b*BM*BKT;
        const unsigned short* cB = sBbase + b*BN*BKT;

        asm volatile("s_waitcnt vmcnt(0)" ::: "memory");
        __builtin_amdgcn_s_barrier();

        // ---- ks = 0: 8 frag reads; stage(t+1); 16 MFMA ----
        {
            bf16x8 av[4], bv[4];
            #pragma unroll
            for (int m = 0; m < 4; ++m) av[m] = rd(cA, wm*64 + m*16 + lr, 0);
            #pragma unroll
            for (int n = 0; n < 4; ++n) bv[n] = rd(cB, wn*64 + n*16 + lr, 0);
            if (t + 1 < NTK) {
                stage(A, aRow0, sAbase + (b^1)*BM*BKT, t+1);
                stage(B, bRow0, sBbase + (b^1)*BN*BKT, t+1);
            }
            __builtin_amdgcn_s_setprio(1);
            #pragma unroll
            for (int m = 0; m < 4; ++m)
              #pragma unroll
              for (int n = 0; n < 4; ++n)
                acc[m][n] = __builtin_amdgcn_mfma_f32_16x16x32_bf16(av[m], bv[n], acc[m][n], 0, 0, 0);
            __builtin_amdgcn_s_setprio(0);
        }
        // ---- ks = 1: 8 frag reads; 16 MFMA ----
        {
            bf16x8 av[4], bv[4];
            #pragma unroll
            for (int m = 0; m < 4; ++m) av[m] = rd(cA, wm*64 + m*16 + lr, 1);
            #pragma unroll
            for (int n = 0; n < 4; ++n) bv[n] = rd(cB, wn*64 + n*16 + lr, 1);
            __builtin_amdgcn_s_setprio(1);
            #pragma unroll
            for (int m = 0; m < 4; ++m)
              #pragma unroll
              for (int n = 0; n < 4; ++n)
                acc[m][n] = __builtin_amdgcn_mfma_f32_16x16x32_bf16(av[m], bv[n], acc[m][n], 0, 0, 0);
            __builtin_amdgcn_s_setprio(0);
        }
    }

    // ---- epilogue: per-wave LDS transpose -> f32x4 C stores ----
    // MFMA C/D map: col = lane&15, row = (lane>>4)*4 + r.
    __syncthreads();   // all waves done reading staging buffers
    float* ep = reinterpret_cast<float*>(smem) + wave * 2048;   // 8 KiB/wave
    const int grow0 = by*BM + wm*64;
    const int gcol0 = bx*BN + wn*64;
    float bv[4];
    #pragma unroll
    for (int n = 0; n < 4; ++n) bv[n] = bias[gcol0 + n*16 + lr];

    #pragma unroll
    for (int c = 0; c < 2; ++c) {
        #pragma unroll
        for (int mm = 0; mm < 2; ++mm) {
            const int m = c*2 + mm;
            #pragma unroll
            for (int n = 0; n < 4; ++n)
                #pragma unroll
                for (int r = 0; r < 4; ++r)
                    ep[(mm*16 + lsl*4 + r)*64 + n*16 + lr] = acc[m][n][r] + bv[n];
        }
        #pragma unroll
        for (int i = 0; i < 8; ++i) {
            const int idx = i*256 + lane*4;
            const int row = idx >> 6, col = idx & 63;
            const float4 v = *reinterpret_cast<const float4*>(&ep[idx]);
            *reinterpret_cast<float4*>(&C[(size_t)(grow0 + c*32 + row)*OUT_F + gcol0 + col]) = v;
        }
    }
}

// ---------------- fallback (ws too small): fused fp32, slow but correct -----
__global__ __launch_bounds__(256) void fallback_prep_kernel(
    const float* __restrict__ grid, const float* __restrict__ coeffs,
    const float* __restrict__ tangents, const float* __restrict__ alive,
    float* __restrict__ gmin, float* __restrict__ scale, float4* __restrict__ H)
{
    int f = blockIdx.x * blockDim.x + threadIdx.x;
    if (f >= IN_F) return;
    float g[KNOTS], c[KNOTS], t[KNOTS], a[KNOTS];
    for (int i = 0; i < KNOTS; ++i) {
        g[i] = grid[f*KNOTS+i];  c[i] = coeffs[f*KNOTS+i];
        t[i] = tangents[f*KNOTS+i]; a[i] = alive[f*KNOTS+i];
    }
    for (int i = 1; i < KNOTS; ++i) {
        float gk=g[i], ck=c[i], tk=t[i], ak=a[i];
        int j = i-1;
        while (j >= 0 && g[j] > gk) { g[j+1]=g[j]; c[j+1]=c[j]; t[j+1]=t[j]; a[j+1]=a[j]; --j; }
        g[j+1]=gk; c[j+1]=ck; t[j+1]=tk; a[j+1]=ak;
    }
    float mcl[KNOTS], mtl[KNOTS];
    for (int i = 0; i < KNOTS; ++i) {
        float s = 1.f / (1.f + expf(-a[i]));
        mcl[i] = c[i]*s;  mtl[i] = t[i]*s;
    }
    gmin[f] = g[0];
    float grange = fmaxf(g[KNOTS-1] - g[0], 1e-6f);
    scale[f] = (float)(KNOTS-1) / grange;
    for (int k = 0; k < KNOTS-1; ++k) {
        float dx = fmaxf(g[k+1]-g[k], 1e-6f);
        H[(size_t)f*KNOTS + k] = make_float4(mcl[k], mcl[k+1], mtl[k]*dx, mtl[k+1]*dx);
    }
    H[(size_t)f*KNOTS + KNOTS-1] = make_float4(0.f, 0.f, 0.f, 0.f);
}

__global__ __launch_bounds__(256) void fallback_kernel(
    const float* __restrict__ x, const float* __restrict__ P,
    const float* __restrict__ R, const float* __restrict__ pb,
    const float* __restrict__ gmin, const float* __restrict__ scale,
    const float4* __restrict__ H, float* __restrict__ out)
{
    __shared__ float s_s[IN_F];
    __shared__ float s_x[IN_F];
    int row = blockIdx.x;
    const float* xr = x + (size_t)row*IN_F;
    for (int f = threadIdx.x; f < IN_F; f += 256) {
        float xi = xr[f];
        float xn = (xi - gmin[f]) * scale[f];
        xn = fminf(fmaxf(xn, 0.f), (float)(KNOTS-1));
        int idx = (int)xn;  idx = idx > (KNOTS-2) ? (KNOTS-2) : idx;
        float tt = xn - (float)idx;
        float4 h = H[(size_t)f*KNOTS + idx];
        float t2 = tt*tt, t3 = t2*tt;
        s_s[f] = (2.f*t3-3.f*t2+1.f)*h.x + (-2.f*t3+3.f*t2)*h.y
               + (t3-2.f*t2+tt)*h.z + (t3-t2)*h.w;
        s_x[f] = xi;
    }
    __syncthreads();
    for (int j = 0; j < 4; ++j) {
        int o = threadIdx.x + j*256;
        const float* Pr = P + (size_t)o*IN_F;
        const float* Rr = R + (size_t)o*IN_F;
        float acc = pb[o];
        for (int f = 0; f < IN_F; ++f)
            acc = fmaf(s_s[f], Pr[f], fmaf(s_x[f], Rr[f], acc));
        out[(size_t)row*OUT_F + o] = acc;
    }
}

extern "C" void kernel_launch(void* const* d_in, const int* in_sizes, int n_in,
                              void* d_out, int out_size, void* d_ws, size_t ws_size,
                              hipStream_t stream) {
    const float* x         = (const float*)d_in[0];
    const float* grid      = (const float*)d_in[1];
    const float* coeffs    = (const float*)d_in[2];
    const float* tangents  = (const float*)d_in[3];
    const float* knotalive = (const float*)d_in[4];
    const float* proj_w    = (const float*)d_in[5];
    const float* proj_b    = (const float*)d_in[6];
    const float* res_w     = (const float*)d_in[7];
    float* out = (float*)d_out;

    const size_t needB  = (size_t)OUT_F * GK * 2;                 // 4 MiB
    const size_t needA  = (size_t)M_ROWS * GK * 2;                // 64 MiB
    const size_t needT  = ((size_t)IN_F*2 + (size_t)IN_F*KNOTS*4) * 4
                        + (size_t)IN_F*KNOTS*8;                   // + Hb

    char* ws = (char*)d_ws;
    if (ws_size >= needB + needA + needT) {
        unsigned short* Bcat = (unsigned short*)ws;
        unsigned short* Abuf = (unsigned short*)(ws + needB);
        float*   gmin = (float*)(ws + needB + needA);
        float*   scl  = gmin + IN_F;
        float4*  H    = (float4*)(scl + IN_F);
        ushort4* Hb   = (ushort4*)(H + (size_t)IN_F*KNOTS);

        prep_bcast_kernel<<<2048 + IN_F/256, 256, 0, stream>>>(
            grid, coeffs, tangents, knotalive, proj_w, res_w, Bcat, gmin, scl, H, Hb);
        spline_kernel<<<dim3(M_ROWS/SROWS, IN_F/128), 256, 0, stream>>>(x, gmin, scl, Hb, Abuf);
        gemm_kernel<<<(M_ROWS/BM)*(OUT_F/BN), 1024, 0, stream>>>(Abuf, Bcat, proj_b, out);
    } else {
        float*  gmin = (float*)ws;
        float*  scl  = gmin + IN_F;
        float4* H    = (float4*)(scl + IN_F);
        fallback_prep_kernel<<<(IN_F+255)/256, 256, 0, stream>>>(grid, coeffs, tangents, knotalive,
                                                                 gmin, scl, H);
        fallback_kernel<<<M_ROWS, 256, 0, stream>>>(x, proj_w, res_w, proj_b,
                                                    gmin, scl, H, out);
    }
}